// Round 3
// baseline (2394.088 us; speedup 1.0000x reference)
//
#include <hip/hip_runtime.h>

// ---------------------------------------------------------------------------
// DynamicPropertyBank fused pipeline for MI355X (gfx950).  Round 3 (= R2 with
// the ext_vector element-address compile error fixed via u32x4 bit_cast).
//
// attn == 1.0 exactly (softmax normalized by its own sum over singleton axis)
// -> upd[b,s,:] = v[b,:]; Wk/Wq/g_sl dead; gi = v@W_ih+b_ih iteration-invariant.
//
// R2 changes vs R1 (which ran 559us @ 22.8% occupancy, VALUBusy 47%):
//  * bank_main LDS 62.5KB -> 20.7KB (weights read from global via L1/L2;
//    moves weight delivery off the LDS pipe onto the idle VMEM pipe) ->
//    4 blocks/CU.
//  * GEMMs computed transposed: D = mfma(Wfrag, Sfrag) = (S@W)^T. Fragment
//    bits are unchanged (B-layout(W) == A-layout(W^T)). Each lane then owns
//    ONE slot row (col=lane&15) and 4-contiguous dims per tile: LN reduces
//    with 4 shuffles instead of 32, prev/state LDS traffic is b64/b128, and
//    the final slot store is a coalesced dwordx4.
//  * bf16 packing via (u+0x8000) + v_perm_b32 (1 op per 2 values) instead of
//    5-op RNE per value.
//  * pv head split into its own MFMA kernel (reads slots from d_out);
//    free-slot norms computed from registers in-kernel.
// ---------------------------------------------------------------------------

typedef __attribute__((ext_vector_type(4))) float f32x4;
typedef __attribute__((ext_vector_type(8))) short s16x8;
typedef __attribute__((ext_vector_type(4))) unsigned u32x4;

#define MFMA16 __builtin_amdgcn_mfma_f32_16x16x32_bf16

#define NB       16384
#define NFRAG    156
#define GIB_OFF  (32 + NFRAG*256)   // float offset of gi' buffer in ws
#define PV_N     147456             // 16384*9
#define SLOT_N   33554432           // 16384*32*64
// frag table: 0..23 Whh | 24..39 W1 | 40..55 W2 | 56..87 Wi | 88..95 Wv
//             | 96..119 W_ih | 120..155 Wh1 (k*4 + ct*2 + kf)

__device__ __forceinline__ unsigned short f2bf(float f){   // RNE (prep kernels)
  unsigned int u = __builtin_bit_cast(unsigned int, f);
  u += 0x7fffu + ((u >> 16) & 1u);
  return (unsigned short)(u >> 16);
}
__device__ __forceinline__ unsigned pk2(float lo, float hi){  // round-half-up pack
  unsigned a = __builtin_bit_cast(unsigned, hi) + 0x8000u;
  unsigned b = __builtin_bit_cast(unsigned, lo) + 0x8000u;
  return __builtin_amdgcn_perm(a, b, 0x07060302u);
}
__device__ __forceinline__ float bflo(unsigned u){ return __builtin_bit_cast(float, u << 16); }
__device__ __forceinline__ float bfhi(unsigned u){ return __builtin_bit_cast(float, u & 0xffff0000u); }
__device__ __forceinline__ float sigm(float x){
  return __builtin_amdgcn_rcpf(1.f + __expf(-x));
}
__device__ __forceinline__ float tanh_(float x){
  return 1.f - 2.f*__builtin_amdgcn_rcpf(1.f + __expf(2.f*x));
}
__device__ __forceinline__ float geluf(float x){   // tanh-form, abs err ~3e-4
  return x * sigm(1.5957691216f*x*(1.f + 0.044715f*x*x));
}

// ---------------------------------------------------------------- prep1 ----
__global__ void prep1_pack(const float* __restrict__ Wi, const float* __restrict__ Wv,
                           const float* __restrict__ Wih, const float* __restrict__ Whh,
                           const float* __restrict__ W1, const float* __restrict__ W2,
                           const float* __restrict__ Wh1, float* __restrict__ wsf){
  int t = blockIdx.x*256 + threadIdx.x;
  if (blockIdx.x == 0 && threadIdx.x < 32) wsf[threadIdx.x] = 0.f;  // free_act acc
  if (t >= NFRAG*64) return;
  int frag = t >> 6, lane = t & 63;
  int q = lane >> 4, idx = lane & 15;
  const float* W; int ncols, ct, kf;
  if      (frag < 24){ W=Whh; ncols=192; ct=frag>>1; kf=frag&1; }
  else if (frag < 40){ int f=frag-24;  W=W1;  ncols=128; ct=f>>1; kf=f&1; }
  else if (frag < 56){ int f=frag-40;  W=W2;  ncols=64;  ct=f>>2; kf=f&3; }
  else if (frag < 88){ int f=frag-56;  W=Wi;  ncols=64;  ct=f>>3; kf=f&7; }
  else if (frag < 96){ int f=frag-88;  W=Wv;  ncols=64;  ct=f>>1; kf=f&1; }
  else if (frag <120){ int f=frag-96;  W=Wih; ncols=192; ct=f>>1; kf=f&1; }
  else               { int f=frag-120; W=Wh1 + (size_t)(f>>2)*2048; ncols=32; ct=(f>>1)&1; kf=f&1; }
  int k0 = kf*32 + q*8;
  int n  = ct*16 + idx;
  unsigned short* dst = (unsigned short*)(wsf + 32) + frag*512 + lane*8;
  #pragma unroll
  for (int j = 0; j < 8; ++j) dst[j] = f2bf(W[(size_t)(k0+j)*ncols + n]);
}

// ---------------------------------------------------------------- prep2 ----
// gi'[b,d] = (v @ W_ih)[d] + b_ih[d] + (d<128 ? b_hh[d] : 0)   (b_hh_n stays
// separate: it sits inside the r-multiply of the n gate)
__global__ __launch_bounds__(256) void prep2_gi(
    const float* __restrict__ wstate, const float* __restrict__ bi,
    const float* __restrict__ bv, const float* __restrict__ bih,
    const float* __restrict__ bhh,
    const float* __restrict__ g_in, const float* __restrict__ b_in,
    float* __restrict__ wsf){
  __shared__ __align__(16) unsigned short sxn[4][1152];   // per-wave 16 x 72
  const f32x4 zf = {0.f,0.f,0.f,0.f};
  int tid = threadIdx.x;
  int w = __builtin_amdgcn_readfirstlane(tid >> 6);
  int lane = tid & 63, q = lane >> 4, idx = lane & 15;
  int br0 = blockIdx.x*64 + w*16;                          // 16 batch rows per wave
  const unsigned short* fb = (const unsigned short*)(wsf + 32);
  float* gib = wsf + GIB_OFF;

  // ---- x = ws @ Wi (16x256 @ 256x64) ----
  s16x8 af[8];
  #pragma unroll
  for (int kf = 0; kf < 8; ++kf){
    const float* src = wstate + (size_t)(br0+idx)*256 + kf*32 + q*8;
    f32x4 p0 = *(const f32x4*)(src);
    f32x4 p1 = *(const f32x4*)(src+4);
    u32x4 u = { pk2(p0[0],p0[1]), pk2(p0[2],p0[3]), pk2(p1[0],p1[1]), pk2(p1[2],p1[3]) };
    af[kf] = __builtin_bit_cast(s16x8, u);
  }
  float xv[4][4];
  #pragma unroll
  for (int ct = 0; ct < 4; ++ct){
    f32x4 acc = zf;
    #pragma unroll
    for (int kf = 0; kf < 8; ++kf)
      acc = MFMA16(af[kf], *(const s16x8*)(fb + (56 + ct*8 + kf)*512 + lane*8), acc, 0,0,0);
    float bb = bi[ct*16+idx];
    #pragma unroll
    for (int e = 0; e < 4; ++e) xv[ct][e] = acc[e] + bb;
  }
  // LN(g_in, b_in), write xn bf16 (A-layout scratch)
  #pragma unroll
  for (int e = 0; e < 4; ++e){
    float s1 = xv[0][e]+xv[1][e]+xv[2][e]+xv[3][e];
    float s2 = xv[0][e]*xv[0][e]+xv[1][e]*xv[1][e]+xv[2][e]*xv[2][e]+xv[3][e]*xv[3][e];
    #pragma unroll
    for (int m = 1; m < 16; m <<= 1){ s1 += __shfl_xor(s1,m); s2 += __shfl_xor(s2,m); }
    float mean = s1*(1.f/64.f);
    float var  = s2*(1.f/64.f) - mean*mean;
    float rs   = __builtin_amdgcn_rsqf(var + 1e-5f);
    #pragma unroll
    for (int ct = 0; ct < 4; ++ct){
      int c = ct*16+idx;
      sxn[w][(q*4+e)*72 + c] = f2bf((xv[ct][e]-mean)*rs*g_in[c] + b_in[c]);
    }
  }
  // ---- v = xn @ Wv + bv ----
  s16x8 xa0 = *(const s16x8*)(&sxn[w][idx*72 + q*8]);
  s16x8 xa1 = *(const s16x8*)(&sxn[w][idx*72 + 32 + q*8]);
  #pragma unroll
  for (int ct = 0; ct < 4; ++ct){
    f32x4 acc = MFMA16(xa0, *(const s16x8*)(fb + (88 + ct*2 + 0)*512 + lane*8), zf, 0,0,0);
    acc       = MFMA16(xa1, *(const s16x8*)(fb + (88 + ct*2 + 1)*512 + lane*8), acc, 0,0,0);
    float bb = bv[ct*16+idx];
    #pragma unroll
    for (int e = 0; e < 4; ++e) sxn[w][(q*4+e)*72 + ct*16+idx] = f2bf(acc[e] + bb);
  }
  // ---- gi' = v @ W_ih + b_ih (+ b_hh for d<128) -> ws ----
  s16x8 va0 = *(const s16x8*)(&sxn[w][idx*72 + q*8]);
  s16x8 va1 = *(const s16x8*)(&sxn[w][idx*72 + 32 + q*8]);
  #pragma unroll
  for (int ct = 0; ct < 12; ++ct){
    f32x4 acc = MFMA16(va0, *(const s16x8*)(fb + (96 + ct*2 + 0)*512 + lane*8), zf, 0,0,0);
    acc       = MFMA16(va1, *(const s16x8*)(fb + (96 + ct*2 + 1)*512 + lane*8), acc, 0,0,0);
    int c = ct*16+idx;
    float bb = bih[c] + (c < 128 ? bhh[c] : 0.f);
    #pragma unroll
    for (int e = 0; e < 4; ++e)
      gib[(size_t)(br0 + q*4 + e)*192 + c] = acc[e] + bb;
  }
}

// ------------------------------------------------------------- bank_main ---
// Transposed compute: D = mfma(Wfrag, Sfrag) = (S@W)^T. Per lane:
// state-row = idx (lane&15), dims d = ct*16 + q*4 + e (q=lane>>4).
__global__ __launch_bounds__(256, 4) void bank_main(
    const float* __restrict__ eps, const float* __restrict__ smu, const float* __restrict__ ssig,
    const float* __restrict__ bhh, const float* __restrict__ b1v, const float* __restrict__ b2v,
    const float* __restrict__ g_mlp, const float* __restrict__ b_mlp,
    float* __restrict__ wsf, float* __restrict__ out){
  __shared__ __align__(16) unsigned short sbuf[4][2176]; // per-wave 16 rows x 136
  __shared__ __align__(16) float sgi[2][192];            // gi' per b (pair)
  __shared__ __align__(16) float sbias[384]; // [0:64) bhh_n |[64:192) b1 |[192:256) b2 |[256:320) g_mlp |[320:384) b_mlp
  __shared__ float sfree[2][23];
  const f32x4 zf = {0.f,0.f,0.f,0.f};
  int tid = threadIdx.x;
  int w = __builtin_amdgcn_readfirstlane(tid >> 6);
  int lane = tid & 63, q = lane >> 4, idx = lane & 15;
  int pair = w >> 1, half = w & 1;
  int b = blockIdx.x*2 + pair;
  const unsigned short* fb = (const unsigned short*)(wsf + 32);
  const float* gib = wsf + GIB_OFF;

  for (int i = tid; i < 384; i += 256){
    float vv;
    if      (i <  64) vv = bhh[128+i];
    else if (i < 192) vv = b1v[i-64];
    else if (i < 256) vv = b2v[i-192];
    else if (i < 320) vv = g_mlp[i-256];
    else              vv = b_mlp[i-320];
    sbias[i] = vv;
  }
  if (half == 0){
    #pragma unroll
    for (int jj = 0; jj < 3; ++jj) sgi[pair][jj*64+lane] = gib[(size_t)b*192 + jj*64 + lane];
  }
  unsigned short* S = &sbuf[w][0];
  int s0 = half*16;
  { // init: slots = mu + sigma*eps, bf16 into S (half-wave per 8 rows)
    int rbase = (lane >> 5)*8;
    int col2  = (lane & 31)*2;
    #pragma unroll
    for (int rr = 0; rr < 8; ++rr){
      int r = rbase + rr, s = s0 + r;
      const float2 ev = *(const float2*)&eps [((size_t)b*32 + s)*64 + col2];
      const float2 mu = *(const float2*)&smu [s*64 + col2];
      const float2 sg = *(const float2*)&ssig[s*64 + col2];
      *(unsigned*)&S[r*136 + col2] = pk2(fmaf(sg.x, ev.x, mu.x), fmaf(sg.y, ev.y, mu.y));
    }
  }
  __syncthreads();

  size_t slotob = (size_t)PV_N + ((size_t)b*32 + s0)*64;
  int dq = q*4;
  float fsq = 0.f;
  #pragma unroll 1
  for (int it = 0; it < 3; ++it){
    // ---- gh^T = Whh^T @ prev^T ----
    s16x8 sf0 = *(const s16x8*)(&S[idx*136 +      q*8]);
    s16x8 sf1 = *(const s16x8*)(&S[idx*136 + 32 + q*8]);
    f32x4 gacc[12];
    #pragma unroll
    for (int ct = 0; ct < 12; ++ct){
      f32x4 a   = MFMA16(*(const s16x8*)(fb + (ct*2+0)*512 + lane*8), sf0, zf, 0,0,0);
      gacc[ct]  = MFMA16(*(const s16x8*)(fb + (ct*2+1)*512 + lane*8), sf1, a,  0,0,0);
    }
    // ---- GRU gates (per lane: row idx, dims ct*16+dq+e) ----
    float nsv[4][4];
    #pragma unroll
    for (int ct = 0; ct < 4; ++ct){
      int d = ct*16 + dq;
      f32x4 gr = *(const f32x4*)&sgi[pair][d];
      f32x4 gz = *(const f32x4*)&sgi[pair][64  + d];
      f32x4 gn = *(const f32x4*)&sgi[pair][128 + d];
      f32x4 bn = *(const f32x4*)&sbias[d];
      uint2 pu = *(const uint2*)&S[idx*136 + d];
      float pvv[4] = { bflo(pu.x), bfhi(pu.x), bflo(pu.y), bfhi(pu.y) };
      #pragma unroll
      for (int e = 0; e < 4; ++e){
        float r = sigm(gr[e] + gacc[ct][e]);
        float z = sigm(gz[e] + gacc[4+ct][e]);
        float n = tanh_(fmaf(r, gacc[8+ct][e] + bn[e], gn[e]));
        nsv[ct][e] = fmaf(z, pvv[e] - n, n);
      }
    }
    // ---- LN (per lane scalar mean/var over its row) ----
    float s1 = 0.f, s2 = 0.f;
    #pragma unroll
    for (int ct = 0; ct < 4; ++ct)
      #pragma unroll
      for (int e = 0; e < 4; ++e){ s1 += nsv[ct][e]; s2 = fmaf(nsv[ct][e], nsv[ct][e], s2); }
    s1 += __shfl_xor(s1, 16); s2 += __shfl_xor(s2, 16);
    s1 += __shfl_xor(s1, 32); s2 += __shfl_xor(s2, 32);
    float mean = s1*(1.f/64.f);
    float var  = fmaf(-mean, mean, s2*(1.f/64.f));
    float rs   = __builtin_amdgcn_rsqf(var + 1e-5f);
    float mrs  = mean*rs;
    #pragma unroll
    for (int ct = 0; ct < 4; ++ct){
      int d = ct*16 + dq;
      f32x4 gm = *(const f32x4*)&sbias[256 + d];
      f32x4 bm = *(const f32x4*)&sbias[320 + d];
      float h[4];
      #pragma unroll
      for (int e = 0; e < 4; ++e)
        h[e] = fmaf(fmaf(nsv[ct][e], rs, -mrs), gm[e], bm[e]);
      uint2 uu = { pk2(h[0],h[1]), pk2(h[2],h[3]) };
      *(uint2*)&S[idx*136 + d] = uu;
    }
    // ---- t = gelu(h @ W1 + b1) ----
    s16x8 h0 = *(const s16x8*)(&S[idx*136 +      q*8]);
    s16x8 h1 = *(const s16x8*)(&S[idx*136 + 32 + q*8]);
    f32x4 macc[8];
    #pragma unroll
    for (int ct = 0; ct < 8; ++ct){
      f32x4 a  = MFMA16(*(const s16x8*)(fb + (24+ct*2+0)*512 + lane*8), h0, zf, 0,0,0);
      macc[ct] = MFMA16(*(const s16x8*)(fb + (24+ct*2+1)*512 + lane*8), h1, a,  0,0,0);
    }
    #pragma unroll
    for (int ct = 0; ct < 8; ++ct){
      int d = ct*16 + dq;
      f32x4 bb = *(const f32x4*)&sbias[64 + d];
      float tv[4];
      #pragma unroll
      for (int e = 0; e < 4; ++e) tv[e] = geluf(macc[ct][e] + bb[e]);
      uint2 uu = { pk2(tv[0],tv[1]), pk2(tv[2],tv[3]) };
      *(uint2*)&S[idx*136 + d] = uu;
    }
    // ---- slots = nsv + t @ W2 + b2 ----
    s16x8 t0 = *(const s16x8*)(&S[idx*136 +      q*8]);
    s16x8 t1 = *(const s16x8*)(&S[idx*136 + 32 + q*8]);
    s16x8 t2 = *(const s16x8*)(&S[idx*136 + 64 + q*8]);
    s16x8 t3 = *(const s16x8*)(&S[idx*136 + 96 + q*8]);
    #pragma unroll
    for (int ct = 0; ct < 4; ++ct){
      f32x4 a = MFMA16(*(const s16x8*)(fb + (40+ct*4+0)*512 + lane*8), t0, zf, 0,0,0);
      a       = MFMA16(*(const s16x8*)(fb + (40+ct*4+1)*512 + lane*8), t1, a,  0,0,0);
      a       = MFMA16(*(const s16x8*)(fb + (40+ct*4+2)*512 + lane*8), t2, a,  0,0,0);
      a       = MFMA16(*(const s16x8*)(fb + (40+ct*4+3)*512 + lane*8), t3, a,  0,0,0);
      int d = ct*16 + dq;
      f32x4 bb = *(const f32x4*)&sbias[192 + d];
      float v0 = nsv[ct][0] + a[0] + bb[0];
      float v1 = nsv[ct][1] + a[1] + bb[1];
      float v2 = nsv[ct][2] + a[2] + bb[2];
      float v3 = nsv[ct][3] + a[3] + bb[3];
      if (it < 2){
        uint2 uu = { pk2(v0,v1), pk2(v2,v3) };
        *(uint2*)&S[idx*136 + d] = uu;
      } else {
        f32x4 o = {v0,v1,v2,v3};
        *(f32x4*)&out[slotob + (size_t)idx*64 + d] = o;
        fsq = fmaf(v0,v0,fsq); fsq = fmaf(v1,v1,fsq);
        fsq = fmaf(v2,v2,fsq); fsq = fmaf(v3,v3,fsq);
      }
    }
  }
  // free-slot norms from registers
  fsq += __shfl_xor(fsq, 16);
  fsq += __shfl_xor(fsq, 32);
  int srow = s0 + idx;
  if (q == 0 && srow >= 9) sfree[pair][srow-9] = sqrtf(fsq);
  __syncthreads();
  if (tid < 23) atomicAdd(&wsf[tid], sfree[0][tid] + sfree[1][tid]);
}

// --------------------------------------------------------------- pv_head ---
// per wave: 16 batch rows x one known-slot k.  hh = gelu(s9 @ Wh1_k + bh1_k),
// pv = sigmoid(hh . Wh2_k + bh2_k)
__global__ __launch_bounds__(256) void pv_head(
    const float* __restrict__ bh1, const float* __restrict__ Wh2,
    const float* __restrict__ bh2, const float* __restrict__ wsf,
    float* __restrict__ out){
  const f32x4 zf = {0.f,0.f,0.f,0.f};
  int tid = threadIdx.x, w = tid >> 6, lane = tid & 63;
  int q = lane >> 4, idx = lane & 15;
  int wid = blockIdx.x*4 + w;          // 0..9215
  int k = wid % 9, b0 = (wid/9)*16;
  const unsigned short* fb = (const unsigned short*)(wsf + 32);
  const float* slots = out + PV_N;
  s16x8 af[2];
  #pragma unroll
  for (int kf = 0; kf < 2; ++kf){
    const float* sp = slots + ((size_t)(b0+idx)*32 + k)*64 + kf*32 + q*8;
    f32x4 p0 = *(const f32x4*)sp;
    f32x4 p1 = *(const f32x4*)(sp+4);
    u32x4 u = { pk2(p0[0],p0[1]), pk2(p0[2],p0[3]), pk2(p1[0],p1[1]), pk2(p1[2],p1[3]) };
    af[kf] = __builtin_bit_cast(s16x8, u);
  }
  float g[2][4];
  #pragma unroll
  for (int ct = 0; ct < 2; ++ct){
    f32x4 a = MFMA16(af[0], *(const s16x8*)(fb + (120+k*4+ct*2+0)*512 + lane*8), zf, 0,0,0);
    a       = MFMA16(af[1], *(const s16x8*)(fb + (120+k*4+ct*2+1)*512 + lane*8), a,  0,0,0);
    float bb = bh1[k*32 + ct*16 + idx];
    #pragma unroll
    for (int e = 0; e < 4; ++e) g[ct][e] = geluf(a[e] + bb);
  }
  float w0 = Wh2[k*32 + idx], w1 = Wh2[k*32 + 16 + idx];
  float bk = bh2[k];
  #pragma unroll
  for (int e = 0; e < 4; ++e){
    float p = fmaf(g[1][e], w1, g[0][e]*w0);
    #pragma unroll
    for (int m = 1; m < 16; m <<= 1) p += __shfl_xor(p, m);
    if (idx == 0) out[(size_t)(b0 + q*4 + e)*9 + k] = sigm(p + bk);
  }
}

// ---------------------------------------------------------------- final ----
__global__ void bank_final(const float* __restrict__ wsf, float* __restrict__ out){
  int t = threadIdx.x;
  if (t < 23) out[(size_t)PV_N + SLOT_N + t] = wsf[t] * (1.f/16384.f);
}

// ---------------------------------------------------------------------------
extern "C" void kernel_launch(void* const* d_in, const int* in_sizes, int n_in,
                              void* d_out, int out_size, void* d_ws, size_t ws_size,
                              hipStream_t stream){
  (void)in_sizes; (void)n_in; (void)out_size; (void)ws_size; // needs ws >= ~12.8 MB
  const float* wstate = (const float*)d_in[0];
  const float* eps    = (const float*)d_in[1];
  const float* smu    = (const float*)d_in[2];
  const float* ssig   = (const float*)d_in[3];
  const float* Wi     = (const float*)d_in[4];
  const float* bi     = (const float*)d_in[5];
  // d_in[6..9] (Wk,bk,Wq,bq) are provably dead (attn==1)
  const float* Wv     = (const float*)d_in[10];
  const float* bv     = (const float*)d_in[11];
  const float* Wih    = (const float*)d_in[12];
  const float* bih    = (const float*)d_in[13];
  const float* Whh    = (const float*)d_in[14];
  const float* bhh    = (const float*)d_in[15];
  const float* W1     = (const float*)d_in[16];
  const float* b1     = (const float*)d_in[17];
  const float* W2     = (const float*)d_in[18];
  const float* b2     = (const float*)d_in[19];
  const float* g_in   = (const float*)d_in[20];
  const float* b_in   = (const float*)d_in[21];
  // d_in[22..23] (g_sl,b_sl) dead
  const float* g_mlp  = (const float*)d_in[24];
  const float* b_mlp  = (const float*)d_in[25];
  const float* Wh1    = (const float*)d_in[26];
  const float* bh1    = (const float*)d_in[27];
  const float* Wh2    = (const float*)d_in[28];
  const float* bh2    = (const float*)d_in[29];
  float* out = (float*)d_out;
  float* wsf = (float*)d_ws;

  prep1_pack<<<dim3(39),   dim3(256), 0, stream>>>(Wi, Wv, Wih, Whh, W1, W2, Wh1, wsf);
  prep2_gi  <<<dim3(256),  dim3(256), 0, stream>>>(wstate, bi, bv, bih, bhh, g_in, b_in, wsf);
  bank_main <<<dim3(8192), dim3(256), 0, stream>>>(eps, smu, ssig, bhh, b1, b2,
                                                   g_mlp, b_mlp, wsf, out);
  pv_head   <<<dim3(2304), dim3(256), 0, stream>>>(bh1, Wh2, bh2, wsf, out);
  bank_final<<<dim3(1),    dim3(64),  0, stream>>>(wsf, out);
}